// Round 1
// baseline (258.269 us; speedup 1.0000x reference)
//
#include <hip/hip_runtime.h>
#include <math.h>

// Problem constants
#define NB   64
#define CC   256
#define TT   64
#define VV   25
#define HID  16
#define NG   5
#define TORSO_CNT 5   // joints 0,1,2,3,20

// output joint position -> source joint (concat order: TORSO, LH, LL, RH, RL)
__constant__ int SRC_J[25] = {0,1,2,3,20,  8,9,10,11,23,24,  16,17,18,19,  4,5,6,7,21,22,  12,13,14,15};
// output joint position -> group index
__constant__ int GRP_J[25] = {0,0,0,0,0,   1,1,1,1,1,1,      2,2,2,2,      3,3,3,3,3,3,   4,4,4,4};

// ---------------- Kernel A: torso pooling (mean + max over T x 5 joints) ----------------
// One wave per (n,c) pair. Lane = t. Each lane reads 5 torso values of its row.
__global__ void pool_kernel(const float* __restrict__ x,
                            float* __restrict__ avg_out,
                            float* __restrict__ max_out) {
    const int wave = threadIdx.x >> 6;           // 0..3
    const int lane = threadIdx.x & 63;           // = t
    const int pair = blockIdx.x * 4 + wave;      // (n*C + c)
    // pair < N*C guaranteed by grid sizing (N*C divisible by 4)
    const long long base = (long long)pair * (TT * VV) + (long long)lane * VV;

    float v0 = x[base + 0];
    float v1 = x[base + 1];
    float v2 = x[base + 2];
    float v3 = x[base + 3];
    float v4 = x[base + 20];

    float s = v0 + v1 + v2 + v3 + v4;
    float m = fmaxf(fmaxf(fmaxf(v0, v1), fmaxf(v2, v3)), v4);

    #pragma unroll
    for (int off = 32; off >= 1; off >>= 1) {
        s += __shfl_xor(s, off, 64);
        m = fmaxf(m, __shfl_xor(m, off, 64));
    }
    if (lane == 0) {
        avg_out[pair] = s * (1.0f / (TT * TORSO_CNT));
        max_out[pair] = m;
    }
}

// ---------------- Kernel B: gate MLPs ----------------
// One block (256 threads) per n.
// gates[n][f][c] = sigmoid( sum_j W2[f][c][j]*(relu(W1[f][j]·avg + b1) + relu(W1[f][j]·mx + b1)) + 2*b2[f][c] )
__global__ void gates_kernel(const float* __restrict__ avg_in,
                             const float* __restrict__ max_in,
                             const float* __restrict__ W1s,   // (5,16,256)
                             const float* __restrict__ b1s,   // (5,16)
                             const float* __restrict__ W2s,   // (5,256,16)
                             const float* __restrict__ b2s,   // (5,256)
                             float* __restrict__ gates) {     // (N,5,256)
    __shared__ float sAvg[CC];
    __shared__ float sMax[CC];
    __shared__ float sHA[NG * HID];
    __shared__ float sHM[NG * HID];

    const int n = blockIdx.x;
    const int tid = threadIdx.x;

    sAvg[tid] = avg_in[n * CC + tid];
    sMax[tid] = max_in[n * CC + tid];
    __syncthreads();

    if (tid < 2 * NG * HID) {              // 160 threads
        const int type = tid / (NG * HID); // 0 = avg, 1 = max
        const int rem  = tid % (NG * HID); // f*16 + j
        const float* p = type ? sMax : sAvg;
        const float* w = W1s + rem * CC;
        float h = b1s[rem];
        #pragma unroll 8
        for (int c = 0; c < CC; ++c) h += w[c] * p[c];
        h = fmaxf(h, 0.0f);
        if (type) sHM[rem] = h; else sHA[rem] = h;
    }
    __syncthreads();

    const int c = tid;
    #pragma unroll
    for (int f = 0; f < NG; ++f) {
        const float* w2 = W2s + (f * CC + c) * HID;
        float g = 2.0f * b2s[f * CC + c];
        #pragma unroll
        for (int j = 0; j < HID; ++j)
            g += w2[j] * (sHA[f * HID + j] + sHM[f * HID + j]);
        gates[(n * NG + f) * CC + c] = 1.0f / (1.0f + expf(-g));
    }
}

// ---------------- Kernel C: scale + joint permutation ----------------
// 4 consecutive output elements per thread, float4 store.
__global__ void apply_kernel(const float* __restrict__ x,
                             const float* __restrict__ gates,
                             float* __restrict__ out,
                             int total4) {
    const int tid = blockIdx.x * blockDim.x + threadIdx.x;
    if (tid >= total4) return;
    const int base = tid * 4;

    float r[4];
    #pragma unroll
    for (int k = 0; k < 4; ++k) {
        const int idx = base + k;
        const unsigned row = (unsigned)idx / VV;   // n*C*T + c*T + t
        const int p = idx - (int)row * VV;         // output joint position
        const unsigned nc = row / TT;              // n*C + c
        const int c = nc & (CC - 1);
        const int n = nc >> 8;                     // /256
        const float g = gates[(n * NG + GRP_J[p]) * CC + c];
        r[k] = x[(long long)row * VV + SRC_J[p]] * g;
    }
    float4 v = make_float4(r[0], r[1], r[2], r[3]);
    *reinterpret_cast<float4*>(out + base) = v;
}

extern "C" void kernel_launch(void* const* d_in, const int* in_sizes, int n_in,
                              void* d_out, int out_size, void* d_ws, size_t ws_size,
                              hipStream_t stream) {
    const float* x   = (const float*)d_in[0];
    const float* W1s = (const float*)d_in[1];
    const float* b1s = (const float*)d_in[2];
    const float* W2s = (const float*)d_in[3];
    const float* b2s = (const float*)d_in[4];
    float* out = (float*)d_out;

    float* avg   = (float*)d_ws;                  // N*C
    float* mx    = avg + NB * CC;                 // N*C
    float* gates = mx + NB * CC;                  // N*5*C

    // Kernel A: N*C waves, 4 waves per block
    pool_kernel<<<(NB * CC) / 4, 256, 0, stream>>>(x, avg, mx);

    // Kernel B: one block per n
    gates_kernel<<<NB, CC, 0, stream>>>(avg, mx, W1s, b1s, W2s, b2s, gates);

    // Kernel C: elementwise apply, 4 elems/thread
    const int total  = NB * CC * TT * VV;         // 26,214,400
    const int total4 = total / 4;                 // 6,553,600
    apply_kernel<<<(total4 + 255) / 256, 256, 0, stream>>>(x, gates, out, total4);
}

// Round 2
// 218.634 us; speedup vs baseline: 1.1813x; 1.1813x over previous
//
#include <hip/hip_runtime.h>
#include <math.h>

// Problem constants
#define NB   64
#define CC   256
#define TT   64
#define VV   25
#define HID  16
#define NG   5
#define ROWF 1600          // floats per (n,c) pair = T*V
#define ROWF4 400          // float4 per (n,c) pair
#define PAIRS 4            // (n,c) pairs per apply block

// torso joints {0,1,2,3,20} as a bitmask
#define TORSO_MASK 0x10000Fu

// output joint position -> source joint (concat order: TORSO, LH, LL, RH, RL)
// packed LUT: src | (grp<<8)
__constant__ int PERM_LUT[25] = {
    0|(0<<8), 1|(0<<8), 2|(0<<8), 3|(0<<8), 20|(0<<8),
    8|(1<<8), 9|(1<<8), 10|(1<<8), 11|(1<<8), 23|(1<<8), 24|(1<<8),
    16|(2<<8), 17|(2<<8), 18|(2<<8), 19|(2<<8),
    4|(3<<8), 5|(3<<8), 6|(3<<8), 7|(3<<8), 21|(3<<8), 22|(3<<8),
    12|(4<<8), 13|(4<<8), 14|(4<<8), 15|(4<<8)
};

// ---------------- Kernel A: torso pooling, fully coalesced float4 reads ----------------
// One wave per (n,c) pair; 4 waves per block. Lane reads float4 i, i+64, ...
__global__ void pool_kernel(const float4* __restrict__ x4,
                            float* __restrict__ avg_out,
                            float* __restrict__ max_out) {
    const int wave = threadIdx.x >> 6;
    const int lane = threadIdx.x & 63;
    const int pair = blockIdx.x * 4 + wave;      // n*C + c
    const int base4 = pair * ROWF4;

    float s = 0.0f;
    float m = -3.4e38f;
    for (int i = lane; i < ROWF4; i += 64) {
        float4 v = x4[base4 + i];
        const int e = 4 * i;                     // element index within pair
        int j = e % 25;                          // joint of first element
        float vals[4] = {v.x, v.y, v.z, v.w};
        #pragma unroll
        for (int k = 0; k < 4; ++k) {
            int jj = j + k;
            if (jj >= 25) jj -= 25;
            if ((TORSO_MASK >> jj) & 1u) {
                s += vals[k];
                m = fmaxf(m, vals[k]);
            }
        }
    }
    #pragma unroll
    for (int off = 32; off >= 1; off >>= 1) {
        s += __shfl_xor(s, off, 64);
        m = fmaxf(m, __shfl_xor(m, off, 64));
    }
    if (lane == 0) {
        avg_out[pair] = s * (1.0f / (TT * 5));
        max_out[pair] = m;
    }
}

// ---------------- Kernel B: gate MLPs (vectorized) ----------------
// One block (256 threads) per n.
__global__ void gates_kernel(const float* __restrict__ avg_in,
                             const float* __restrict__ max_in,
                             const float* __restrict__ W1s,   // (5,16,256)
                             const float* __restrict__ b1s,   // (5,16)
                             const float* __restrict__ W2s,   // (5,256,16)
                             const float* __restrict__ b2s,   // (5,256)
                             float* __restrict__ gates) {     // (N,5,256)
    __shared__ float4 sAvg[CC / 4];
    __shared__ float4 sMax[CC / 4];
    __shared__ float sHA[NG * HID];
    __shared__ float sHM[NG * HID];

    const int n = blockIdx.x;
    const int tid = threadIdx.x;

    if (tid < 64)       sAvg[tid]      = reinterpret_cast<const float4*>(avg_in + n * CC)[tid];
    else if (tid < 128) sMax[tid - 64] = reinterpret_cast<const float4*>(max_in + n * CC)[tid - 64];
    __syncthreads();

    if (tid < 2 * NG * HID) {              // 160 threads
        const int type = tid / (NG * HID); // 0 = avg, 1 = max
        const int rem  = tid % (NG * HID); // f*16 + j
        const float4* p = type ? sMax : sAvg;
        const float4* w = reinterpret_cast<const float4*>(W1s + rem * CC);
        float h = b1s[rem];
        #pragma unroll 8
        for (int c4 = 0; c4 < CC / 4; ++c4) {
            float4 a = w[c4], b = p[c4];
            h += a.x * b.x + a.y * b.y + a.z * b.z + a.w * b.w;
        }
        h = fmaxf(h, 0.0f);
        if (type) sHM[rem] = h; else sHA[rem] = h;
    }
    __syncthreads();

    const int c = tid;
    #pragma unroll
    for (int f = 0; f < NG; ++f) {
        const float4* w2 = reinterpret_cast<const float4*>(W2s + (f * CC + c) * HID);
        float g = 2.0f * b2s[f * CC + c];
        #pragma unroll
        for (int j4 = 0; j4 < HID / 4; ++j4) {
            float4 w = w2[j4];
            const int jb = f * HID + j4 * 4;
            g += w.x * (sHA[jb + 0] + sHM[jb + 0]);
            g += w.y * (sHA[jb + 1] + sHM[jb + 1]);
            g += w.z * (sHA[jb + 2] + sHM[jb + 2]);
            g += w.w * (sHA[jb + 3] + sHM[jb + 3]);
        }
        gates[(n * NG + f) * CC + c] = 1.0f / (1.0f + expf(-g));
    }
}

// ---------------- Kernel C: LDS-staged scale + joint permutation ----------------
// Block of 256 threads handles PAIRS consecutive (n,c) pairs.
__global__ void apply_kernel(const float4* __restrict__ x4,
                             const float* __restrict__ gates,
                             float4* __restrict__ out4) {
    __shared__ float lds[PAIRS * ROWF];
    __shared__ float sg[PAIRS * NG];
    __shared__ int sLut[VV];

    const int tid = threadIdx.x;
    const int nc0 = blockIdx.x * PAIRS;
    const int base4 = nc0 * ROWF4;

    // coalesced load of PAIRS row-blocks into LDS
    #pragma unroll
    for (int i = tid; i < PAIRS * ROWF4; i += 256) {
        reinterpret_cast<float4*>(lds)[i] = x4[base4 + i];
    }
    if (tid < PAIRS * NG) {                 // 20 gate values
        const int q = tid / NG, f = tid % NG;
        const int nc = nc0 + q;
        sg[tid] = gates[((nc >> 8) * NG + f) * CC + (nc & (CC - 1))];
    }
    if (tid < VV) sLut[tid] = PERM_LUT[tid];
    __syncthreads();

    #pragma unroll
    for (int i = tid; i < PAIRS * ROWF4; i += 256) {
        const int q = i / ROWF4;
        const int e0 = 4 * (i - q * ROWF4);   // first element index within pair
        int row = e0 / 25;
        int p   = e0 - row * 25;
        const float* lrow = lds + q * ROWF;
        const float* gq   = sg + q * NG;
        float r[4];
        #pragma unroll
        for (int k = 0; k < 4; ++k) {
            const int lut = sLut[p];
            r[k] = lrow[row * 25 + (lut & 0xFF)] * gq[lut >> 8];
            ++p;
            if (p >= 25) { p = 0; ++row; }
        }
        out4[base4 + i] = make_float4(r[0], r[1], r[2], r[3]);
    }
}

extern "C" void kernel_launch(void* const* d_in, const int* in_sizes, int n_in,
                              void* d_out, int out_size, void* d_ws, size_t ws_size,
                              hipStream_t stream) {
    const float* x   = (const float*)d_in[0];
    const float* W1s = (const float*)d_in[1];
    const float* b1s = (const float*)d_in[2];
    const float* W2s = (const float*)d_in[3];
    const float* b2s = (const float*)d_in[4];

    float* avg   = (float*)d_ws;                  // N*C
    float* mx    = avg + NB * CC;                 // N*C
    float* gates = mx + NB * CC;                  // N*5*C

    // Kernel A: one wave per (n,c), 4 waves/block
    pool_kernel<<<(NB * CC) / 4, 256, 0, stream>>>(
        (const float4*)x, avg, mx);

    // Kernel B: one block per n
    gates_kernel<<<NB, CC, 0, stream>>>(avg, mx, W1s, b1s, W2s, b2s, gates);

    // Kernel C: PAIRS (n,c) pairs per block
    apply_kernel<<<(NB * CC) / PAIRS, 256, 0, stream>>>(
        (const float4*)x, gates, (float4*)d_out);
}